// Round 5
// baseline (303.955 us; speedup 1.0000x reference)
//
#include <hip/hip_runtime.h>
#include <hip/hip_fp16.h>

#define N_NODES 100000
#define E_EDGES 1600000
#define F_IN    256
#define F_HID   64
#define F_OUT   16
#define NBKT    391           // buckets of 256 dst-nodes (99999>>8 = 390)
#define CAP     4608          // region size per bucket (mean 4092, +8 sigma)
#define GEMM1_BLOCKS 782      // ceil(N/128)
#define PA_BLOCKS    782      // 2048 edges each

typedef _Float16 half8   __attribute__((ext_vector_type(8)));
typedef float    floatx4 __attribute__((ext_vector_type(4)));

// ---------------------------------------------------------------------------
// K1 (fused, block-specialized, PARITY-INTERLEAVED): odd blocks run passA
// (bucket scatter), even blocks run the MFMA gemm1 (support1 = x @ W1).
// Parity interleave (vs range split) keeps a gemm/passA mix resident on
// every CU for the whole kernel, so x-load latency overlaps passA's
// atomic/scatter latency. Round-4 range-split showed phase serialization
// (dur = sum of phases, occupancy 33%). Atomics still live ONLY in passA
// blocks — same-WAVE fusion of atomics with MFMA poisons vmcnt waits
// (round-1: ~5x slowdown); separate waves are safe.
// ---------------------------------------------------------------------------
__global__ __launch_bounds__(256) void gemm1_passA_kernel(const float* __restrict__ x,
                                                          const float* __restrict__ W1,
                                                          _Float16* __restrict__ support1,
                                                          const int* __restrict__ esrc,
                                                          const int* __restrict__ edst,
                                                          const float* __restrict__ evals,
                                                          int* __restrict__ bucketCursor,
                                                          int2* __restrict__ tmp) {
    __shared__ __align__(16) char ldsbuf[32768];
    const int t = threadIdx.x;
    const int vb = blockIdx.x >> 1;      // virtual block id within role

    if (blockIdx.x & 1) {
        // ---- passA: 2048 edges per block ----
        int* hist = (int*)ldsbuf;          // NBKT ints
        int* base = hist + NBKT;           // NBKT ints
        for (int i = t; i < NBKT; i += 256) hist[i] = 0;
        __syncthreads();
        const int base_e = vb * 2048;
        int rks[2][4];
#pragma unroll
        for (int ch = 0; ch < 2; ++ch) {
            const int e0 = base_e + ch * 1024 + t * 4;
            if (e0 < E_EDGES) {
                int4 d4 = *(const int4*)&edst[e0];
                rks[ch][0] = atomicAdd(&hist[d4.x >> 8], 1);
                rks[ch][1] = atomicAdd(&hist[d4.y >> 8], 1);
                rks[ch][2] = atomicAdd(&hist[d4.z >> 8], 1);
                rks[ch][3] = atomicAdd(&hist[d4.w >> 8], 1);
            }
        }
        __syncthreads();
        for (int i = t; i < NBKT; i += 256) {
            const int h = hist[i];
            if (h) base[i] = atomicAdd(&bucketCursor[i], h);
        }
        __syncthreads();
#pragma unroll
        for (int ch = 0; ch < 2; ++ch) {
            const int e0 = base_e + ch * 1024 + t * 4;
            if (e0 < E_EDGES) {
                int4 d4 = *(const int4*)&edst[e0];    // L1-hot reload
                int4 s4 = *(const int4*)&esrc[e0];
                float4 v4 = *(const float4*)&evals[e0];
                const int dd[4] = {d4.x, d4.y, d4.z, d4.w};
                const int ss[4] = {s4.x, s4.y, s4.z, s4.w};
                const float vv[4] = {v4.x, v4.y, v4.z, v4.w};
#pragma unroll
                for (int u = 0; u < 4; ++u) {
                    const int bu = dd[u] >> 8;
                    const int bpos = base[bu] + rks[ch][u];
                    if (bpos < CAP)   // 8-sigma safety clamp, never hit
                        tmp[(size_t)bu * CAP + bpos] =
                            make_int2(((dd[u] & 255) << 17) | ss[u],
                                      __float_as_int(vv[u]));
                }
            }
        }
        return;
    }

    // ---- MFMA gemm1: stage W1 fp32 -> f16 frag-order LDS ----
    _Float16* Bs = (_Float16*)ldsbuf;   // 32 KB
    for (int i = t; i < 16384; i += 256) {
        const int k = i >> 6, n = i & 63;
        const int kb = k >> 5, quad = (k >> 3) & 3, j = k & 7;
        const int nt = n >> 4, ln = n & 15;
        Bs[((kb * 4 + nt) * 64 + quad * 16 + ln) * 8 + j] = (_Float16)W1[i];
    }
    __syncthreads();

    const int wave = t >> 6;
    const int lane = t & 63;
    const int ln   = lane & 15;
    const int quad = lane >> 4;
    const int row0 = vb * 128 + wave * 32;

    const float* xp[2];
#pragma unroll
    for (int mt = 0; mt < 2; ++mt) {
        int r = row0 + mt * 16 + ln;
        if (r > N_NODES - 1) r = N_NODES - 1;
        xp[mt] = x + (size_t)r * F_IN + quad * 8;
    }

    floatx4 acc[2][4] = {};

#pragma unroll 4
    for (int kb = 0; kb < 8; ++kb) {
        half8 a[2];
#pragma unroll
        for (int mt = 0; mt < 2; ++mt) {
            float4 v0 = *(const float4*)(xp[mt] + kb * 32);
            float4 v1 = *(const float4*)(xp[mt] + kb * 32 + 4);
            half8 h;
            h[0] = (_Float16)v0.x; h[1] = (_Float16)v0.y;
            h[2] = (_Float16)v0.z; h[3] = (_Float16)v0.w;
            h[4] = (_Float16)v1.x; h[5] = (_Float16)v1.y;
            h[6] = (_Float16)v1.z; h[7] = (_Float16)v1.w;
            a[mt] = h;
        }
#pragma unroll
        for (int nt = 0; nt < 4; ++nt) {
            half8 b = *(const half8*)&Bs[((size_t)((kb * 4 + nt) * 64 + lane)) * 8];
            acc[0][nt] = __builtin_amdgcn_mfma_f32_16x16x32_f16(a[0], b, acc[0][nt], 0, 0, 0);
            acc[1][nt] = __builtin_amdgcn_mfma_f32_16x16x32_f16(a[1], b, acc[1][nt], 0, 0, 0);
        }
    }

#pragma unroll
    for (int mt = 0; mt < 2; ++mt) {
        const int rbase = row0 + mt * 16 + quad * 4;
#pragma unroll
        for (int r = 0; r < 4; ++r) {
            const int row = rbase + r;
            if (row < N_NODES) {
#pragma unroll
                for (int nt = 0; nt < 4; ++nt)
                    support1[(size_t)row * F_HID + nt * 16 + ln] = (_Float16)acc[mt][nt][r];
            }
        }
    }
}

// ---------------------------------------------------------------------------
// K2: passB — one block per 256-node bucket (391 blocks). LDS degree hist +
// scan + cursors; re-sort within the L2-resident CAP region to node order.
// ---------------------------------------------------------------------------
__global__ __launch_bounds__(256) void passB_kernel(const int2* __restrict__ tmp,
                                                    const int* __restrict__ bucketCursor,
                                                    int2* __restrict__ sorted_edges,
                                                    int* __restrict__ rowstart,
                                                    int* __restrict__ deg) {
    __shared__ int ldeg[256];
    __shared__ int lcur[256];
    __shared__ int s[256];
    const int t = threadIdx.x;
    const int b = blockIdx.x;
    const int beg = b * CAP;
    int cnt = bucketCursor[b];
    if (cnt > CAP) cnt = CAP;

    ldeg[t] = 0;
    __syncthreads();

    for (int p = t; p < cnt; p += 256) {
        int2 r = tmp[beg + p];
        atomicAdd(&ldeg[r.x >> 17], 1);
    }
    __syncthreads();

    const int v = ldeg[t];
    s[t] = v;
    __syncthreads();
#pragma unroll
    for (int off = 1; off < 256; off <<= 1) {
        const int y = (t >= off) ? s[t - off] : 0;
        __syncthreads();
        s[t] += y;
        __syncthreads();
    }
    const int run = s[t] - v;   // exclusive prefix
    lcur[t] = run;
    const int node = b * 256 + t;
    if (node < N_NODES) { rowstart[node] = beg + run; deg[node] = v; }
    __syncthreads();

    for (int p = t; p < cnt; p += 256) {
        int2 r = tmp[beg + p];
        const int pos = beg + atomicAdd(&lcur[r.x >> 17], 1);
        sorted_edges[pos] = make_int2(r.x & 0x1FFFF, r.y);
    }
}

// ---------------------------------------------------------------------------
// K3 fused: per dst node (one wave): h = relu(sum_e w*support1[src] + b1),
// support2[node] = h @ W2 (f16 out).
// OCTET-gather: lane (p8 = lane>>3 edge-parity 0..7, c8 = lane&7 feature
// octet) handles edges 8k+p8 via shfl broadcast, one uint4 (16 B, feats
// 8c8..8c8+7) per edge — one wave-load covers 8 support1 rows, u=0..3
// unroll keeps 32 rows in flight. Reduce across parities shfl_xor(8,16,32).
// ---------------------------------------------------------------------------
__global__ __launch_bounds__(256) void spmm1_fused_kernel(const int* __restrict__ rowstart,
                                                          const int* __restrict__ deg,
                                                          const int2* __restrict__ sorted_edges,
                                                          const _Float16* __restrict__ support1,
                                                          const float* __restrict__ b1,
                                                          const float* __restrict__ W2,
                                                          _Float16* __restrict__ support2) {
    __shared__ float W2s[64 * 17];   // padded stride 17
    __shared__ float b1s[64];
    __shared__ __align__(16) float hs[4][64];
    const int t = threadIdx.x;
    for (int i = t; i < 1024; i += 256)
        W2s[(i >> 4) * 17 + (i & 15)] = W2[i];
    if (t < 64) b1s[t] = b1[t];
    __syncthreads();

    const int wave = t >> 6;
    const int lane = t & 63;
    const int node = blockIdx.x * 4 + wave;   // grid exact: 25000*4
    const int c8 = lane & 7;                  // feature octet
    const int p8 = lane >> 3;                 // edge parity 0..7

    const int beg = rowstart[node];
    const int cnt = deg[node];

    int   src_l = 0;
    float val_l = 0.f;
    if (lane < cnt) {
        int2 ev = sorted_edges[beg + lane];
        src_l = ev.x;
        val_l = __int_as_float(ev.y);
    }

    float acc[8] = {};
    const int kmax = cnt < 64 ? cnt : 64;
    const int octs = (kmax + 7) >> 3;
    const int op   = (octs + 3) & ~3;         // pad: w=0 slots are no-ops
    for (int k = 0; k < op; k += 4) {
        float w[4]; uint4 d[4];
#pragma unroll
        for (int u = 0; u < 4; ++u) {
            const int idx = 8 * (k + u) + p8; // <= 63
            const int s2  = __shfl(src_l, idx);
            w[u] = __shfl(val_l, idx);
            d[u] = *(const uint4*)&support1[(size_t)s2 * F_HID + 8 * c8];
        }
#pragma unroll
        for (int u = 0; u < 4; ++u) {
            const _Float16* hp = (const _Float16*)&d[u];
#pragma unroll
            for (int i = 0; i < 8; ++i)
                acc[i] = fmaf(w[u], (float)hp[i], acc[i]);
        }
    }
    for (int k = 64 + p8; k < cnt; k += 8) {  // rare tail, parity-split
        int2 ev = sorted_edges[beg + k];
        const float w = __int_as_float(ev.y);
        const uint4 d = *(const uint4*)&support1[(size_t)ev.x * F_HID + 8 * c8];
        const _Float16* hp = (const _Float16*)&d;
#pragma unroll
        for (int i = 0; i < 8; ++i)
            acc[i] = fmaf(w, (float)hp[i], acc[i]);
    }

#pragma unroll
    for (int i = 0; i < 8; ++i) {
        acc[i] += __shfl_xor(acc[i], 8);
        acc[i] += __shfl_xor(acc[i], 16);
        acc[i] += __shfl_xor(acc[i], 32);
    }
    if (p8 == 0) {
        float4 h0, h1;
        h0.x = fmaxf(acc[0] + b1s[8 * c8 + 0], 0.f);
        h0.y = fmaxf(acc[1] + b1s[8 * c8 + 1], 0.f);
        h0.z = fmaxf(acc[2] + b1s[8 * c8 + 2], 0.f);
        h0.w = fmaxf(acc[3] + b1s[8 * c8 + 3], 0.f);
        h1.x = fmaxf(acc[4] + b1s[8 * c8 + 4], 0.f);
        h1.y = fmaxf(acc[5] + b1s[8 * c8 + 5], 0.f);
        h1.z = fmaxf(acc[6] + b1s[8 * c8 + 6], 0.f);
        h1.w = fmaxf(acc[7] + b1s[8 * c8 + 7], 0.f);
        *(float4*)&hs[wave][8 * c8]     = h0;
        *(float4*)&hs[wave][8 * c8 + 4] = h1;
    }
    __syncthreads();

    // Epilogue h @ W2: quad covers a 16-k segment, reduce across quads.
    const int ln   = lane & 15;
    const int quad = lane >> 4;
    float o = 0.f;
#pragma unroll
    for (int kk = 0; kk < 16; ++kk) {
        const int k2 = quad * 16 + kk;
        o = fmaf(hs[wave][k2], W2s[k2 * 17 + ln], o);
    }
    o += __shfl_xor(o, 16);
    o += __shfl_xor(o, 32);
    if (quad == 0)
        support2[(size_t)node * F_OUT + ln] = (_Float16)o;
}

// ---------------------------------------------------------------------------
// K4 fused: per dst node (16 lanes): logits = sum_e w*support2[src] + b2,
// then log_softmax. OCTET-gather at width 16: lane (p = j>>1 parity 0..7,
// c = j&1 feat-octet) handles edges 8u+p, uint4 loads (feats 8c..8c+7);
// both 16-edge batches issued unconditionally (4 loads in flight; w=0 pads
// are no-ops). Combine via shfl_xor(2,4,8); softmax across c via
// shfl_xor(1); two float4 stores per node.
// ---------------------------------------------------------------------------
__global__ __launch_bounds__(256) void spmm2_fused_kernel(const int* __restrict__ rowstart,
                                                          const int* __restrict__ deg,
                                                          const int2* __restrict__ sorted_edges,
                                                          const _Float16* __restrict__ support2,
                                                          const float* __restrict__ b2,
                                                          float* __restrict__ out) {
    __shared__ float b2s[16];
    const int t = threadIdx.x;
    if (t < 16) b2s[t] = b2[t];
    __syncthreads();

    const int j    = t & 15;
    const int node = blockIdx.x * 16 + (t >> 4);   // grid exact: 6250*16
    const int c = j & 1;                           // feature octet
    const int p = j >> 1;                          // edge parity 0..7

    const int beg = rowstart[node];
    const int cnt = deg[node];

    int   src_a = 0, src_b = 0;
    float val_a = 0.f, val_b = 0.f;
    if (j < cnt)      { int2 ev = sorted_edges[beg + j];      src_a = ev.x; val_a = __int_as_float(ev.y); }
    if (j + 16 < cnt) { int2 ev = sorted_edges[beg + 16 + j]; src_b = ev.x; val_b = __int_as_float(ev.y); }

    float acc[8] = {};
    {   // edges 0..31 (batch b zero-padded when cnt<=16)
        float w[4]; uint4 d[4];
#pragma unroll
        for (int u = 0; u < 2; ++u) {
            const int idx = 8 * u + p;
            const int s2  = __shfl(src_a, idx, 16);
            w[u] = __shfl(val_a, idx, 16);
            d[u] = *(const uint4*)&support2[(size_t)s2 * F_OUT + 8 * c];
        }
#pragma unroll
        for (int u = 0; u < 2; ++u) {
            const int idx = 8 * u + p;
            const int s2  = __shfl(src_b, idx, 16);
            w[2 + u] = __shfl(val_b, idx, 16);
            d[2 + u] = *(const uint4*)&support2[(size_t)s2 * F_OUT + 8 * c];
        }
#pragma unroll
        for (int u = 0; u < 4; ++u) {
            const _Float16* hp = (const _Float16*)&d[u];
#pragma unroll
            for (int i = 0; i < 8; ++i)
                acc[i] = fmaf(w[u], (float)hp[i], acc[i]);
        }
    }
    for (int k = 32 + p; k < cnt; k += 8) {   // rare tail, parity-split
        int2 ev = sorted_edges[beg + k];
        const float w = __int_as_float(ev.y);
        const uint4 d = *(const uint4*)&support2[(size_t)ev.x * F_OUT + 8 * c];
        const _Float16* hp = (const _Float16*)&d;
#pragma unroll
        for (int i = 0; i < 8; ++i)
            acc[i] = fmaf(w, (float)hp[i], acc[i]);
    }

#pragma unroll
    for (int i = 0; i < 8; ++i) {
        acc[i] += __shfl_xor(acc[i], 2, 16);
        acc[i] += __shfl_xor(acc[i], 4, 16);
        acc[i] += __shfl_xor(acc[i], 8, 16);
    }

    float v[8];
#pragma unroll
    for (int i = 0; i < 8; ++i) v[i] = acc[i] + b2s[8 * c + i];
    float m = fmaxf(fmaxf(fmaxf(v[0], v[1]), fmaxf(v[2], v[3])),
                    fmaxf(fmaxf(v[4], v[5]), fmaxf(v[6], v[7])));
    m = fmaxf(m, __shfl_xor(m, 1, 16));
    float sum = __expf(v[0] - m) + __expf(v[1] - m) + __expf(v[2] - m) + __expf(v[3] - m)
              + __expf(v[4] - m) + __expf(v[5] - m) + __expf(v[6] - m) + __expf(v[7] - m);
    sum += __shfl_xor(sum, 1, 16);
    if (p == 0) {
        const float lse = m + __logf(sum);
        *(float4*)&out[(size_t)node * F_OUT + 8 * c] =
            make_float4(v[0] - lse, v[1] - lse, v[2] - lse, v[3] - lse);
        *(float4*)&out[(size_t)node * F_OUT + 8 * c + 4] =
            make_float4(v[4] - lse, v[5] - lse, v[6] - lse, v[7] - lse);
    }
}

// ---------------------------------------------------------------------------
extern "C" void kernel_launch(void* const* d_in, const int* in_sizes, int n_in,
                              void* d_out, int out_size, void* d_ws, size_t ws_size,
                              hipStream_t stream) {
    const float* x     = (const float*)d_in[0];
    const int*   esrc  = (const int*)  d_in[1];
    const int*   edst  = (const int*)  d_in[2];
    const float* evals = (const float*)d_in[3];
    const float* W1    = (const float*)d_in[4];
    const float* b1    = (const float*)d_in[5];
    const float* W2    = (const float*)d_in[6];
    const float* b2    = (const float*)d_in[7];
    float* out = (float*)d_out;

    // Workspace layout (~45.6 MB); all segments 16 B-aligned.
    char* ws = (char*)d_ws;
    _Float16* support1     = (_Float16*)(ws);              // 12,800,000 B
    _Float16* support2     = (_Float16*)(ws + 12800000);   //  3,200,000 B
    int2*     tmp          = (int2*)    (ws + 16000000);   // 14,413,824 B (NBKT*CAP*8)
    int2*     sorted_edges = (int2*)    (ws + 30413824);   // 14,413,824 B
    int*      rowstart     = (int*)     (ws + 44827648);   //    400,000 B
    int*      deg          = (int*)     (ws + 45227648);   //    400,000 B
    int*      bucketCursor = (int*)     (ws + 45627648);   //      1,568 B

    hipMemsetAsync(bucketCursor, 0, NBKT * sizeof(int), stream);
    gemm1_passA_kernel<<<GEMM1_BLOCKS + PA_BLOCKS, 256, 0, stream>>>(
        x, W1, support1, esrc, edst, evals, bucketCursor, tmp);
    passB_kernel<<<NBKT, 256, 0, stream>>>(tmp, bucketCursor, sorted_edges, rowstart, deg);
    spmm1_fused_kernel<<<N_NODES / 4, 256, 0, stream>>>(rowstart, deg, sorted_edges,
                                                        support1, b1, W2, support2);
    spmm2_fused_kernel<<<N_NODES / 16, 256, 0, stream>>>(rowstart, deg, sorted_edges,
                                                         support2, b2, out);
}

// Round 6
// 294.730 us; speedup vs baseline: 1.0313x; 1.0313x over previous
//
#include <hip/hip_runtime.h>
#include <hip/hip_fp16.h>

#define N_NODES 100000
#define E_EDGES 1600000
#define F_IN    256
#define F_HID   64
#define F_OUT   16
#define NBKT    391           // buckets of 256 dst-nodes (99999>>8 = 390)
#define CAP     4608          // region size per bucket (mean 4092, +8 sigma)
#define GEMM1_BLOCKS 782      // ceil(N/128)
#define PA_BLOCKS    782      // 2048 edges each

typedef _Float16 half8   __attribute__((ext_vector_type(8)));
typedef float    floatx4 __attribute__((ext_vector_type(4)));

// ---------------------------------------------------------------------------
// K0: prep — zero bucketCursor + convert W1 fp32 -> f16 in MFMA B-fragment
// order (global, 32 KB, shared by all gemm blocks via L2). Replaces both the
// hipMemsetAsync and the per-block 32 KB LDS staging of W1 (which capped K1
// at 5 blocks/CU and 29% occupancy in rounds 0-5).
// ---------------------------------------------------------------------------
__global__ __launch_bounds__(256) void prep_kernel(const float* __restrict__ W1,
                                                   _Float16* __restrict__ W1h,
                                                   int* __restrict__ bucketCursor) {
    const int i = blockIdx.x * 256 + threadIdx.x;   // grid: 64 blocks -> i < 16384
    if (i < NBKT) bucketCursor[i] = 0;
    const int k = i >> 6, n = i & 63;
    const int kb = k >> 5, quad = (k >> 3) & 3, j = k & 7;
    const int nt = n >> 4, ln = n & 15;
    W1h[((kb * 4 + nt) * 64 + quad * 16 + ln) * 8 + j] = (_Float16)W1[i];
}

// ---------------------------------------------------------------------------
// K1 (fused, block-specialized, range-split): blocks [0,GEMM1_BLOCKS) run
// the MFMA gemm1 (support1 = x @ W1h); blocks after run passA (bucket
// scatter). LDS is only passA's 3.1 KB histogram -> 8 blocks/CU (wave cap),
// all 1564 blocks co-resident (~24 waves/CU) for latency hiding. B-frags
// load straight from W1h (L2-hot, 16 B/lane coalesced). Atomics live ONLY
// in passA blocks — same-WAVE fusion of atomics with MFMA poisons vmcnt
// waits (round-1: ~5x slowdown); separate waves are safe.
// ---------------------------------------------------------------------------
__global__ __launch_bounds__(256) void gemm1_passA_kernel(const float* __restrict__ x,
                                                          const _Float16* __restrict__ W1h,
                                                          _Float16* __restrict__ support1,
                                                          const int* __restrict__ esrc,
                                                          const int* __restrict__ edst,
                                                          const float* __restrict__ evals,
                                                          int* __restrict__ bucketCursor,
                                                          int2* __restrict__ tmp) {
    __shared__ int hist[NBKT];
    __shared__ int base[NBKT];
    const int t = threadIdx.x;

    if (blockIdx.x >= GEMM1_BLOCKS) {
        // ---- passA: 2048 edges per block ----
        const int blk = blockIdx.x - GEMM1_BLOCKS;
        for (int i = t; i < NBKT; i += 256) hist[i] = 0;
        __syncthreads();
        const int base_e = blk * 2048;
        int rks[2][4];
#pragma unroll
        for (int ch = 0; ch < 2; ++ch) {
            const int e0 = base_e + ch * 1024 + t * 4;
            if (e0 < E_EDGES) {
                int4 d4 = *(const int4*)&edst[e0];
                rks[ch][0] = atomicAdd(&hist[d4.x >> 8], 1);
                rks[ch][1] = atomicAdd(&hist[d4.y >> 8], 1);
                rks[ch][2] = atomicAdd(&hist[d4.z >> 8], 1);
                rks[ch][3] = atomicAdd(&hist[d4.w >> 8], 1);
            }
        }
        __syncthreads();
        for (int i = t; i < NBKT; i += 256) {
            const int h = hist[i];
            if (h) base[i] = atomicAdd(&bucketCursor[i], h);
        }
        __syncthreads();
#pragma unroll
        for (int ch = 0; ch < 2; ++ch) {
            const int e0 = base_e + ch * 1024 + t * 4;
            if (e0 < E_EDGES) {
                int4 d4 = *(const int4*)&edst[e0];    // L1-hot reload
                int4 s4 = *(const int4*)&esrc[e0];
                float4 v4 = *(const float4*)&evals[e0];
                const int dd[4] = {d4.x, d4.y, d4.z, d4.w};
                const int ss[4] = {s4.x, s4.y, s4.z, s4.w};
                const float vv[4] = {v4.x, v4.y, v4.z, v4.w};
#pragma unroll
                for (int u = 0; u < 4; ++u) {
                    const int bu = dd[u] >> 8;
                    const int bpos = base[bu] + rks[ch][u];
                    if (bpos < CAP)   // 8-sigma safety clamp, never hit
                        tmp[(size_t)bu * CAP + bpos] =
                            make_int2(((dd[u] & 255) << 17) | ss[u],
                                      __float_as_int(vv[u]));
                }
            }
        }
        return;
    }

    // ---- MFMA gemm1: B-frags direct from W1h (global, L2-hot) ----
    const int wave = t >> 6;
    const int lane = t & 63;
    const int ln   = lane & 15;
    const int quad = lane >> 4;
    const int row0 = blockIdx.x * 128 + wave * 32;

    const float* xp[2];
#pragma unroll
    for (int mt = 0; mt < 2; ++mt) {
        int r = row0 + mt * 16 + ln;
        if (r > N_NODES - 1) r = N_NODES - 1;
        xp[mt] = x + (size_t)r * F_IN + quad * 8;
    }

    floatx4 acc[2][4] = {};

#pragma unroll 4
    for (int kb = 0; kb < 8; ++kb) {
        half8 a[2];
#pragma unroll
        for (int mt = 0; mt < 2; ++mt) {
            float4 v0 = *(const float4*)(xp[mt] + kb * 32);
            float4 v1 = *(const float4*)(xp[mt] + kb * 32 + 4);
            half8 h;
            h[0] = (_Float16)v0.x; h[1] = (_Float16)v0.y;
            h[2] = (_Float16)v0.z; h[3] = (_Float16)v0.w;
            h[4] = (_Float16)v1.x; h[5] = (_Float16)v1.y;
            h[6] = (_Float16)v1.z; h[7] = (_Float16)v1.w;
            a[mt] = h;
        }
#pragma unroll
        for (int nt = 0; nt < 4; ++nt) {
            half8 b = *(const half8*)&W1h[((size_t)((kb * 4 + nt) * 64 + lane)) * 8];
            acc[0][nt] = __builtin_amdgcn_mfma_f32_16x16x32_f16(a[0], b, acc[0][nt], 0, 0, 0);
            acc[1][nt] = __builtin_amdgcn_mfma_f32_16x16x32_f16(a[1], b, acc[1][nt], 0, 0, 0);
        }
    }

#pragma unroll
    for (int mt = 0; mt < 2; ++mt) {
        const int rbase = row0 + mt * 16 + quad * 4;
#pragma unroll
        for (int r = 0; r < 4; ++r) {
            const int row = rbase + r;
            if (row < N_NODES) {
#pragma unroll
                for (int nt = 0; nt < 4; ++nt)
                    support1[(size_t)row * F_HID + nt * 16 + ln] = (_Float16)acc[mt][nt][r];
            }
        }
    }
}

// ---------------------------------------------------------------------------
// K2: passB — one block per 256-node bucket (391 blocks). LDS degree hist +
// scan + cursors; re-sort within the L2-resident CAP region to node order.
// ---------------------------------------------------------------------------
__global__ __launch_bounds__(256) void passB_kernel(const int2* __restrict__ tmp,
                                                    const int* __restrict__ bucketCursor,
                                                    int2* __restrict__ sorted_edges,
                                                    int* __restrict__ rowstart,
                                                    int* __restrict__ deg) {
    __shared__ int ldeg[256];
    __shared__ int lcur[256];
    __shared__ int s[256];
    const int t = threadIdx.x;
    const int b = blockIdx.x;
    const int beg = b * CAP;
    int cnt = bucketCursor[b];
    if (cnt > CAP) cnt = CAP;

    ldeg[t] = 0;
    __syncthreads();

    for (int p = t; p < cnt; p += 256) {
        int2 r = tmp[beg + p];
        atomicAdd(&ldeg[r.x >> 17], 1);
    }
    __syncthreads();

    const int v = ldeg[t];
    s[t] = v;
    __syncthreads();
#pragma unroll
    for (int off = 1; off < 256; off <<= 1) {
        const int y = (t >= off) ? s[t - off] : 0;
        __syncthreads();
        s[t] += y;
        __syncthreads();
    }
    const int run = s[t] - v;   // exclusive prefix
    lcur[t] = run;
    const int node = b * 256 + t;
    if (node < N_NODES) { rowstart[node] = beg + run; deg[node] = v; }
    __syncthreads();

    for (int p = t; p < cnt; p += 256) {
        int2 r = tmp[beg + p];
        const int pos = beg + atomicAdd(&lcur[r.x >> 17], 1);
        sorted_edges[pos] = make_int2(r.x & 0x1FFFF, r.y);
    }
}

// ---------------------------------------------------------------------------
// K3 fused: per dst node (one wave): h = relu(sum_e w*support1[src] + b1),
// support2[node] = h @ W2 (f16 out).
// OCTET-gather: lane (p8 = lane>>3 edge-parity 0..7, c8 = lane&7 feature
// octet) handles edges 8k+p8 via shfl broadcast, one uint4 (16 B, feats
// 8c8..8c8+7) per edge — one wave-load covers 8 support1 rows, u=0..3
// unroll keeps 32 rows in flight. Reduce across parities shfl_xor(8,16,32).
// ---------------------------------------------------------------------------
__global__ __launch_bounds__(256) void spmm1_fused_kernel(const int* __restrict__ rowstart,
                                                          const int* __restrict__ deg,
                                                          const int2* __restrict__ sorted_edges,
                                                          const _Float16* __restrict__ support1,
                                                          const float* __restrict__ b1,
                                                          const float* __restrict__ W2,
                                                          _Float16* __restrict__ support2) {
    __shared__ float W2s[64 * 17];   // padded stride 17
    __shared__ float b1s[64];
    __shared__ __align__(16) float hs[4][64];
    const int t = threadIdx.x;
    for (int i = t; i < 1024; i += 256)
        W2s[(i >> 4) * 17 + (i & 15)] = W2[i];
    if (t < 64) b1s[t] = b1[t];
    __syncthreads();

    const int wave = t >> 6;
    const int lane = t & 63;
    const int node = blockIdx.x * 4 + wave;   // grid exact: 25000*4
    const int c8 = lane & 7;                  // feature octet
    const int p8 = lane >> 3;                 // edge parity 0..7

    const int beg = rowstart[node];
    const int cnt = deg[node];

    int   src_l = 0;
    float val_l = 0.f;
    if (lane < cnt) {
        int2 ev = sorted_edges[beg + lane];
        src_l = ev.x;
        val_l = __int_as_float(ev.y);
    }

    float acc[8] = {};
    const int kmax = cnt < 64 ? cnt : 64;
    const int octs = (kmax + 7) >> 3;
    const int op   = (octs + 3) & ~3;         // pad: w=0 slots are no-ops
    for (int k = 0; k < op; k += 4) {
        float w[4]; uint4 d[4];
#pragma unroll
        for (int u = 0; u < 4; ++u) {
            const int idx = 8 * (k + u) + p8; // <= 63
            const int s2  = __shfl(src_l, idx);
            w[u] = __shfl(val_l, idx);
            d[u] = *(const uint4*)&support1[(size_t)s2 * F_HID + 8 * c8];
        }
#pragma unroll
        for (int u = 0; u < 4; ++u) {
            const _Float16* hp = (const _Float16*)&d[u];
#pragma unroll
            for (int i = 0; i < 8; ++i)
                acc[i] = fmaf(w[u], (float)hp[i], acc[i]);
        }
    }
    for (int k = 64 + p8; k < cnt; k += 8) {  // rare tail, parity-split
        int2 ev = sorted_edges[beg + k];
        const float w = __int_as_float(ev.y);
        const uint4 d = *(const uint4*)&support1[(size_t)ev.x * F_HID + 8 * c8];
        const _Float16* hp = (const _Float16*)&d;
#pragma unroll
        for (int i = 0; i < 8; ++i)
            acc[i] = fmaf(w, (float)hp[i], acc[i]);
    }

#pragma unroll
    for (int i = 0; i < 8; ++i) {
        acc[i] += __shfl_xor(acc[i], 8);
        acc[i] += __shfl_xor(acc[i], 16);
        acc[i] += __shfl_xor(acc[i], 32);
    }
    if (p8 == 0) {
        float4 h0, h1;
        h0.x = fmaxf(acc[0] + b1s[8 * c8 + 0], 0.f);
        h0.y = fmaxf(acc[1] + b1s[8 * c8 + 1], 0.f);
        h0.z = fmaxf(acc[2] + b1s[8 * c8 + 2], 0.f);
        h0.w = fmaxf(acc[3] + b1s[8 * c8 + 3], 0.f);
        h1.x = fmaxf(acc[4] + b1s[8 * c8 + 4], 0.f);
        h1.y = fmaxf(acc[5] + b1s[8 * c8 + 5], 0.f);
        h1.z = fmaxf(acc[6] + b1s[8 * c8 + 6], 0.f);
        h1.w = fmaxf(acc[7] + b1s[8 * c8 + 7], 0.f);
        *(float4*)&hs[wave][8 * c8]     = h0;
        *(float4*)&hs[wave][8 * c8 + 4] = h1;
    }
    __syncthreads();

    // Epilogue h @ W2: quad covers a 16-k segment, reduce across quads.
    const int ln   = lane & 15;
    const int quad = lane >> 4;
    float o = 0.f;
#pragma unroll
    for (int kk = 0; kk < 16; ++kk) {
        const int k2 = quad * 16 + kk;
        o = fmaf(hs[wave][k2], W2s[k2 * 17 + ln], o);
    }
    o += __shfl_xor(o, 16);
    o += __shfl_xor(o, 32);
    if (quad == 0)
        support2[(size_t)node * F_OUT + ln] = (_Float16)o;
}

// ---------------------------------------------------------------------------
// K4 fused: per dst node (16 lanes): logits = sum_e w*support2[src] + b2,
// then log_softmax. OCTET-gather at width 16: lane (p = j>>1 parity 0..7,
// c = j&1 feat-octet) handles edges 8u+p, uint4 loads (feats 8c..8c+7);
// both 16-edge batches issued unconditionally (4 loads in flight; w=0 pads
// are no-ops). Combine via shfl_xor(2,4,8); softmax across c via
// shfl_xor(1); two float4 stores per node.
// ---------------------------------------------------------------------------
__global__ __launch_bounds__(256) void spmm2_fused_kernel(const int* __restrict__ rowstart,
                                                          const int* __restrict__ deg,
                                                          const int2* __restrict__ sorted_edges,
                                                          const _Float16* __restrict__ support2,
                                                          const float* __restrict__ b2,
                                                          float* __restrict__ out) {
    __shared__ float b2s[16];
    const int t = threadIdx.x;
    if (t < 16) b2s[t] = b2[t];
    __syncthreads();

    const int j    = t & 15;
    const int node = blockIdx.x * 16 + (t >> 4);   // grid exact: 6250*16
    const int c = j & 1;                           // feature octet
    const int p = j >> 1;                          // edge parity 0..7

    const int beg = rowstart[node];
    const int cnt = deg[node];

    int   src_a = 0, src_b = 0;
    float val_a = 0.f, val_b = 0.f;
    if (j < cnt)      { int2 ev = sorted_edges[beg + j];      src_a = ev.x; val_a = __int_as_float(ev.y); }
    if (j + 16 < cnt) { int2 ev = sorted_edges[beg + 16 + j]; src_b = ev.x; val_b = __int_as_float(ev.y); }

    float acc[8] = {};
    {   // edges 0..31 (batch b zero-padded when cnt<=16)
        float w[4]; uint4 d[4];
#pragma unroll
        for (int u = 0; u < 2; ++u) {
            const int idx = 8 * u + p;
            const int s2  = __shfl(src_a, idx, 16);
            w[u] = __shfl(val_a, idx, 16);
            d[u] = *(const uint4*)&support2[(size_t)s2 * F_OUT + 8 * c];
        }
#pragma unroll
        for (int u = 0; u < 2; ++u) {
            const int idx = 8 * u + p;
            const int s2  = __shfl(src_b, idx, 16);
            w[2 + u] = __shfl(val_b, idx, 16);
            d[2 + u] = *(const uint4*)&support2[(size_t)s2 * F_OUT + 8 * c];
        }
#pragma unroll
        for (int u = 0; u < 4; ++u) {
            const _Float16* hp = (const _Float16*)&d[u];
#pragma unroll
            for (int i = 0; i < 8; ++i)
                acc[i] = fmaf(w[u], (float)hp[i], acc[i]);
        }
    }
    for (int k = 32 + p; k < cnt; k += 8) {   // rare tail, parity-split
        int2 ev = sorted_edges[beg + k];
        const float w = __int_as_float(ev.y);
        const uint4 d = *(const uint4*)&support2[(size_t)ev.x * F_OUT + 8 * c];
        const _Float16* hp = (const _Float16*)&d;
#pragma unroll
        for (int i = 0; i < 8; ++i)
            acc[i] = fmaf(w, (float)hp[i], acc[i]);
    }

#pragma unroll
    for (int i = 0; i < 8; ++i) {
        acc[i] += __shfl_xor(acc[i], 2, 16);
        acc[i] += __shfl_xor(acc[i], 4, 16);
        acc[i] += __shfl_xor(acc[i], 8, 16);
    }

    float v[8];
#pragma unroll
    for (int i = 0; i < 8; ++i) v[i] = acc[i] + b2s[8 * c + i];
    float m = fmaxf(fmaxf(fmaxf(v[0], v[1]), fmaxf(v[2], v[3])),
                    fmaxf(fmaxf(v[4], v[5]), fmaxf(v[6], v[7])));
    m = fmaxf(m, __shfl_xor(m, 1, 16));
    float sum = __expf(v[0] - m) + __expf(v[1] - m) + __expf(v[2] - m) + __expf(v[3] - m)
              + __expf(v[4] - m) + __expf(v[5] - m) + __expf(v[6] - m) + __expf(v[7] - m);
    sum += __shfl_xor(sum, 1, 16);
    if (p == 0) {
        const float lse = m + __logf(sum);
        *(float4*)&out[(size_t)node * F_OUT + 8 * c] =
            make_float4(v[0] - lse, v[1] - lse, v[2] - lse, v[3] - lse);
        *(float4*)&out[(size_t)node * F_OUT + 8 * c + 4] =
            make_float4(v[4] - lse, v[5] - lse, v[6] - lse, v[7] - lse);
    }
}

// ---------------------------------------------------------------------------
extern "C" void kernel_launch(void* const* d_in, const int* in_sizes, int n_in,
                              void* d_out, int out_size, void* d_ws, size_t ws_size,
                              hipStream_t stream) {
    const float* x     = (const float*)d_in[0];
    const int*   esrc  = (const int*)  d_in[1];
    const int*   edst  = (const int*)  d_in[2];
    const float* evals = (const float*)d_in[3];
    const float* W1    = (const float*)d_in[4];
    const float* b1    = (const float*)d_in[5];
    const float* W2    = (const float*)d_in[6];
    const float* b2    = (const float*)d_in[7];
    float* out = (float*)d_out;

    // Workspace layout (~45.7 MB); all segments 16 B-aligned.
    char* ws = (char*)d_ws;
    _Float16* support1     = (_Float16*)(ws);              // 12,800,000 B
    _Float16* support2     = (_Float16*)(ws + 12800000);   //  3,200,000 B
    int2*     tmp          = (int2*)    (ws + 16000000);   // 14,413,824 B (NBKT*CAP*8)
    int2*     sorted_edges = (int2*)    (ws + 30413824);   // 14,413,824 B
    int*      rowstart     = (int*)     (ws + 44827648);   //    400,000 B
    int*      deg          = (int*)     (ws + 45227648);   //    400,000 B
    int*      bucketCursor = (int*)     (ws + 45627648);   //      1,568 B
    _Float16* W1h          = (_Float16*)(ws + 45629216);   //     32,768 B

    prep_kernel<<<64, 256, 0, stream>>>(W1, W1h, bucketCursor);
    gemm1_passA_kernel<<<GEMM1_BLOCKS + PA_BLOCKS, 256, 0, stream>>>(
        x, W1h, support1, esrc, edst, evals, bucketCursor, tmp);
    passB_kernel<<<NBKT, 256, 0, stream>>>(tmp, bucketCursor, sorted_edges, rowstart, deg);
    spmm1_fused_kernel<<<N_NODES / 4, 256, 0, stream>>>(rowstart, deg, sorted_edges,
                                                        support1, b1, W2, support2);
    spmm2_fused_kernel<<<N_NODES / 16, 256, 0, stream>>>(rowstart, deg, sorted_edges,
                                                         support2, b2, out);
}

// Round 7
// 285.462 us; speedup vs baseline: 1.0648x; 1.0325x over previous
//
#include <hip/hip_runtime.h>
#include <hip/hip_fp16.h>

#define N_NODES 100000
#define E_EDGES 1600000
#define F_IN    256
#define F_HID   64
#define F_OUT   16
#define NBKT    391           // buckets of 256 dst-nodes (99999>>8 = 390)
#define CAP     4608          // region size per bucket (mean 4092, +8 sigma)
#define GEMM1_BLOCKS 782      // ceil(N/128)
#define PA_BLOCKS    782      // 2048 edges each

typedef _Float16 half8   __attribute__((ext_vector_type(8)));
typedef _Float16 half2v  __attribute__((ext_vector_type(2)));
typedef float    floatx4 __attribute__((ext_vector_type(4)));

// ---------------------------------------------------------------------------
// K0: prep — zero bucketCursor + convert W1 fp32 -> f16 in MFMA B-fragment
// order (global, 32 KB, shared by all gemm blocks via L2). Replaces both the
// hipMemsetAsync and the per-block 32 KB LDS staging of W1 (which capped K1
// at 5 blocks/CU and 29% occupancy in rounds 0-5).
// ---------------------------------------------------------------------------
__global__ __launch_bounds__(256) void prep_kernel(const float* __restrict__ W1,
                                                   _Float16* __restrict__ W1h,
                                                   int* __restrict__ bucketCursor) {
    const int i = blockIdx.x * 256 + threadIdx.x;   // grid: 64 blocks -> i < 16384
    if (i < NBKT) bucketCursor[i] = 0;
    const int k = i >> 6, n = i & 63;
    const int kb = k >> 5, quad = (k >> 3) & 3, j = k & 7;
    const int nt = n >> 4, ln = n & 15;
    W1h[((kb * 4 + nt) * 64 + quad * 16 + ln) * 8 + j] = (_Float16)W1[i];
}

// ---------------------------------------------------------------------------
// K1 (fused, block-specialized, range-split): blocks [0,GEMM1_BLOCKS) run
// the MFMA gemm1 (support1 = x @ W1h); blocks after run passA (bucket
// scatter). LDS is only passA's 3.1 KB histogram -> high occupancy; B-frags
// load straight from W1h (L2-hot, 16 B/lane coalesced). Atomics live ONLY
// in passA blocks — same-WAVE fusion of atomics with MFMA poisons vmcnt
// waits (round-1: ~5x slowdown); separate waves are safe.
// ---------------------------------------------------------------------------
__global__ __launch_bounds__(256) void gemm1_passA_kernel(const float* __restrict__ x,
                                                          const _Float16* __restrict__ W1h,
                                                          _Float16* __restrict__ support1,
                                                          const int* __restrict__ esrc,
                                                          const int* __restrict__ edst,
                                                          const float* __restrict__ evals,
                                                          int* __restrict__ bucketCursor,
                                                          int2* __restrict__ tmp) {
    __shared__ int hist[NBKT];
    __shared__ int base[NBKT];
    const int t = threadIdx.x;

    if (blockIdx.x >= GEMM1_BLOCKS) {
        // ---- passA: 2048 edges per block ----
        const int blk = blockIdx.x - GEMM1_BLOCKS;
        for (int i = t; i < NBKT; i += 256) hist[i] = 0;
        __syncthreads();
        const int base_e = blk * 2048;
        int rks[2][4];
#pragma unroll
        for (int ch = 0; ch < 2; ++ch) {
            const int e0 = base_e + ch * 1024 + t * 4;
            if (e0 < E_EDGES) {
                int4 d4 = *(const int4*)&edst[e0];
                rks[ch][0] = atomicAdd(&hist[d4.x >> 8], 1);
                rks[ch][1] = atomicAdd(&hist[d4.y >> 8], 1);
                rks[ch][2] = atomicAdd(&hist[d4.z >> 8], 1);
                rks[ch][3] = atomicAdd(&hist[d4.w >> 8], 1);
            }
        }
        __syncthreads();
        for (int i = t; i < NBKT; i += 256) {
            const int h = hist[i];
            if (h) base[i] = atomicAdd(&bucketCursor[i], h);
        }
        __syncthreads();
#pragma unroll
        for (int ch = 0; ch < 2; ++ch) {
            const int e0 = base_e + ch * 1024 + t * 4;
            if (e0 < E_EDGES) {
                int4 d4 = *(const int4*)&edst[e0];    // L1-hot reload
                int4 s4 = *(const int4*)&esrc[e0];
                float4 v4 = *(const float4*)&evals[e0];
                const int dd[4] = {d4.x, d4.y, d4.z, d4.w};
                const int ss[4] = {s4.x, s4.y, s4.z, s4.w};
                const float vv[4] = {v4.x, v4.y, v4.z, v4.w};
#pragma unroll
                for (int u = 0; u < 4; ++u) {
                    const int bu = dd[u] >> 8;
                    const int bpos = base[bu] + rks[ch][u];
                    if (bpos < CAP)   // 8-sigma safety clamp, never hit
                        tmp[(size_t)bu * CAP + bpos] =
                            make_int2(((dd[u] & 255) << 17) | ss[u],
                                      __float_as_int(vv[u]));
                }
            }
        }
        return;
    }

    // ---- MFMA gemm1: B-frags direct from W1h (global, L2-hot) ----
    const int wave = t >> 6;
    const int lane = t & 63;
    const int ln   = lane & 15;
    const int quad = lane >> 4;
    const int row0 = blockIdx.x * 128 + wave * 32;

    const float* xp[2];
#pragma unroll
    for (int mt = 0; mt < 2; ++mt) {
        int r = row0 + mt * 16 + ln;
        if (r > N_NODES - 1) r = N_NODES - 1;
        xp[mt] = x + (size_t)r * F_IN + quad * 8;
    }

    floatx4 acc[2][4] = {};

#pragma unroll 4
    for (int kb = 0; kb < 8; ++kb) {
        half8 a[2];
#pragma unroll
        for (int mt = 0; mt < 2; ++mt) {
            float4 v0 = *(const float4*)(xp[mt] + kb * 32);
            float4 v1 = *(const float4*)(xp[mt] + kb * 32 + 4);
            half8 h;
            h[0] = (_Float16)v0.x; h[1] = (_Float16)v0.y;
            h[2] = (_Float16)v0.z; h[3] = (_Float16)v0.w;
            h[4] = (_Float16)v1.x; h[5] = (_Float16)v1.y;
            h[6] = (_Float16)v1.z; h[7] = (_Float16)v1.w;
            a[mt] = h;
        }
#pragma unroll
        for (int nt = 0; nt < 4; ++nt) {
            half8 b = *(const half8*)&W1h[((size_t)((kb * 4 + nt) * 64 + lane)) * 8];
            acc[0][nt] = __builtin_amdgcn_mfma_f32_16x16x32_f16(a[0], b, acc[0][nt], 0, 0, 0);
            acc[1][nt] = __builtin_amdgcn_mfma_f32_16x16x32_f16(a[1], b, acc[1][nt], 0, 0, 0);
        }
    }

#pragma unroll
    for (int mt = 0; mt < 2; ++mt) {
        const int rbase = row0 + mt * 16 + quad * 4;
#pragma unroll
        for (int r = 0; r < 4; ++r) {
            const int row = rbase + r;
            if (row < N_NODES) {
#pragma unroll
                for (int nt = 0; nt < 4; ++nt)
                    support1[(size_t)row * F_HID + nt * 16 + ln] = (_Float16)acc[mt][nt][r];
            }
        }
    }
}

// ---------------------------------------------------------------------------
// K2: passB — one block per 256-node bucket (391 blocks). LDS degree hist +
// scan + cursors; re-sort within the L2-resident CAP region to node order.
// ---------------------------------------------------------------------------
__global__ __launch_bounds__(256) void passB_kernel(const int2* __restrict__ tmp,
                                                    const int* __restrict__ bucketCursor,
                                                    int2* __restrict__ sorted_edges,
                                                    int* __restrict__ rowstart,
                                                    int* __restrict__ deg) {
    __shared__ int ldeg[256];
    __shared__ int lcur[256];
    __shared__ int s[256];
    const int t = threadIdx.x;
    const int b = blockIdx.x;
    const int beg = b * CAP;
    int cnt = bucketCursor[b];
    if (cnt > CAP) cnt = CAP;

    ldeg[t] = 0;
    __syncthreads();

    for (int p = t; p < cnt; p += 256) {
        int2 r = tmp[beg + p];
        atomicAdd(&ldeg[r.x >> 17], 1);
    }
    __syncthreads();

    const int v = ldeg[t];
    s[t] = v;
    __syncthreads();
#pragma unroll
    for (int off = 1; off < 256; off <<= 1) {
        const int y = (t >= off) ? s[t - off] : 0;
        __syncthreads();
        s[t] += y;
        __syncthreads();
    }
    const int run = s[t] - v;   // exclusive prefix
    lcur[t] = run;
    const int node = b * 256 + t;
    if (node < N_NODES) { rowstart[node] = beg + run; deg[node] = v; }
    __syncthreads();

    for (int p = t; p < cnt; p += 256) {
        int2 r = tmp[beg + p];
        const int pos = beg + atomicAdd(&lcur[r.x >> 17], 1);
        sorted_edges[pos] = make_int2(r.x & 0x1FFFF, r.y);
    }
}

// ---------------------------------------------------------------------------
// K3 fused: per dst node (one wave): h = relu(sum_e w*support1[src] + b1),
// support2[node] = h @ W2 (f16 out).
// QUAD-gather (round-3-proven; octet version wasted ~50% slots as w=0 pads
// at mean deg 16): lane (q = lane>>4 edge-parity, c4 = lane&15 feature-quad)
// handles edges 4k+q via shfl broadcast, one uint2 (8 B) gather per edge.
// Inner-loop cost cut: packed v_pk_fma_f16 accumulation (2 ops/slot vs
// 4 cvt + 4 fma) and 32-bit gather addressing. f32 cross-lane reduction.
// ---------------------------------------------------------------------------
__global__ __launch_bounds__(256) void spmm1_fused_kernel(const int* __restrict__ rowstart,
                                                          const int* __restrict__ deg,
                                                          const int2* __restrict__ sorted_edges,
                                                          const _Float16* __restrict__ support1,
                                                          const float* __restrict__ b1,
                                                          const float* __restrict__ W2,
                                                          _Float16* __restrict__ support2) {
    __shared__ float W2s[64 * 17];   // padded stride 17
    __shared__ float b1s[64];
    __shared__ __align__(16) float hs[4][64];
    const int t = threadIdx.x;
    for (int i = t; i < 1024; i += 256)
        W2s[(i >> 4) * 17 + (i & 15)] = W2[i];
    if (t < 64) b1s[t] = b1[t];
    __syncthreads();

    const int wave = t >> 6;
    const int lane = t & 63;
    const int node = blockIdx.x * 4 + wave;   // grid exact: 25000*4
    const int c4 = lane & 15;                 // feature quad
    const int q  = lane >> 4;                 // edge parity 0..3

    const int beg = rowstart[node];
    const int cnt = deg[node];

    int   src_l = 0;
    float val_l = 0.f;
    if (lane < cnt) {
        int2 ev = sorted_edges[beg + lane];
        src_l = ev.x;
        val_l = __int_as_float(ev.y);
    }

    half2v a01 = {(_Float16)0, (_Float16)0};
    half2v a23 = {(_Float16)0, (_Float16)0};
    const int kmax  = cnt < 64 ? cnt : 64;
    const int quads = (kmax + 3) >> 2;
    const int qp    = (quads + 3) & ~3;       // pad: w=0 slots are no-ops
    for (int k = 0; k < qp; k += 4) {
        float w[4]; uint2 d[4];
#pragma unroll
        for (int u = 0; u < 4; ++u) {
            const int idx = 4 * (k + u) + q;  // <= 63
            const int s2  = __shfl(src_l, idx);
            w[u] = __shfl(val_l, idx);
            d[u] = *(const uint2*)&support1[(s2 << 6) + 4 * c4];
        }
#pragma unroll
        for (int u = 0; u < 4; ++u) {
            const half2v* hp = (const half2v*)&d[u];
            const _Float16 wh = (_Float16)w[u];
            const half2v w2 = {wh, wh};
            a01 += w2 * hp[0];
            a23 += w2 * hp[1];
        }
    }
    for (int k = 64 + q; k < cnt; k += 4) {   // rare tail, parity-split
        int2 ev = sorted_edges[beg + k];
        const uint2 d = *(const uint2*)&support1[(ev.x << 6) + 4 * c4];
        const half2v* hp = (const half2v*)&d;
        const _Float16 wh = (_Float16)__int_as_float(ev.y);
        const half2v w2 = {wh, wh};
        a01 += w2 * hp[0];
        a23 += w2 * hp[1];
    }

    float acc0 = (float)a01[0], acc1 = (float)a01[1];
    float acc2 = (float)a23[0], acc3 = (float)a23[1];
    acc0 += __shfl_xor(acc0, 16); acc0 += __shfl_xor(acc0, 32);
    acc1 += __shfl_xor(acc1, 16); acc1 += __shfl_xor(acc1, 32);
    acc2 += __shfl_xor(acc2, 16); acc2 += __shfl_xor(acc2, 32);
    acc3 += __shfl_xor(acc3, 16); acc3 += __shfl_xor(acc3, 32);
    if (q == 0) {
        float4 hv;
        hv.x = fmaxf(acc0 + b1s[4 * c4],     0.f);
        hv.y = fmaxf(acc1 + b1s[4 * c4 + 1], 0.f);
        hv.z = fmaxf(acc2 + b1s[4 * c4 + 2], 0.f);
        hv.w = fmaxf(acc3 + b1s[4 * c4 + 3], 0.f);
        *(float4*)&hs[wave][4 * c4] = hv;
    }
    __syncthreads();

    // Epilogue h @ W2: quad covers a 16-k segment, reduce across quads.
    const int ln   = lane & 15;
    const int quad = lane >> 4;
    float o = 0.f;
#pragma unroll
    for (int kk = 0; kk < 16; ++kk) {
        const int k2 = quad * 16 + kk;
        o = fmaf(hs[wave][k2], W2s[k2 * 17 + ln], o);
    }
    o += __shfl_xor(o, 16);
    o += __shfl_xor(o, 32);
    if (quad == 0)
        support2[(size_t)node * F_OUT + ln] = (_Float16)o;
}

// ---------------------------------------------------------------------------
// K4 fused: per dst node (16 lanes): logits = sum_e w*support2[src] + b2,
// then log_softmax. QUAD-gather at width 16 (round-3-proven): lane (p=j>>2,
// c=j&3) handles edges 4k+p, uint2 loads (features 4c..4c+3); packed
// v_pk_fma_f16 accumulation + 32-bit addressing; combine via shfl_xor(4,8);
// softmax reduce over c via shfl_xor(1,2); float4 output.
// ---------------------------------------------------------------------------
__global__ __launch_bounds__(256) void spmm2_fused_kernel(const int* __restrict__ rowstart,
                                                          const int* __restrict__ deg,
                                                          const int2* __restrict__ sorted_edges,
                                                          const _Float16* __restrict__ support2,
                                                          const float* __restrict__ b2,
                                                          float* __restrict__ out) {
    __shared__ float b2s[16];
    const int t = threadIdx.x;
    if (t < 16) b2s[t] = b2[t];
    __syncthreads();

    const int j    = t & 15;
    const int node = blockIdx.x * 16 + (t >> 4);   // grid exact: 6250*16
    const int c = j & 3;
    const int p = j >> 2;

    const int beg = rowstart[node];
    const int cnt = deg[node];

    int   src_a = 0, src_b = 0;
    float val_a = 0.f, val_b = 0.f;
    if (j < cnt)      { int2 ev = sorted_edges[beg + j];      src_a = ev.x; val_a = __int_as_float(ev.y); }
    if (j + 16 < cnt) { int2 ev = sorted_edges[beg + 16 + j]; src_b = ev.x; val_b = __int_as_float(ev.y); }

    half2v a01 = {(_Float16)0, (_Float16)0};
    half2v a23 = {(_Float16)0, (_Float16)0};
    {   // batch 1: edges 0..15 (4 quad-iters; w=0 beyond cnt)
        float w[4]; uint2 d[4];
#pragma unroll
        for (int u = 0; u < 4; ++u) {
            const int idx = 4 * u + p;
            const int s2  = __shfl(src_a, idx, 16);
            w[u] = __shfl(val_a, idx, 16);
            d[u] = *(const uint2*)&support2[(s2 << 4) + 4 * c];
        }
#pragma unroll
        for (int u = 0; u < 4; ++u) {
            const half2v* hp = (const half2v*)&d[u];
            const _Float16 wh = (_Float16)w[u];
            const half2v w2 = {wh, wh};
            a01 += w2 * hp[0];
            a23 += w2 * hp[1];
        }
    }
    if (cnt > 16) {   // batch 2: edges 16..31
        float w[4]; uint2 d[4];
#pragma unroll
        for (int u = 0; u < 4; ++u) {
            const int idx = 4 * u + p;
            const int s2  = __shfl(src_b, idx, 16);
            w[u] = __shfl(val_b, idx, 16);
            d[u] = *(const uint2*)&support2[(s2 << 4) + 4 * c];
        }
#pragma unroll
        for (int u = 0; u < 4; ++u) {
            const half2v* hp = (const half2v*)&d[u];
            const _Float16 wh = (_Float16)w[u];
            const half2v w2 = {wh, wh};
            a01 += w2 * hp[0];
            a23 += w2 * hp[1];
        }
    }
    for (int k = 32 + p; k < cnt; k += 4) {   // rare tail, parity-split
        int2 ev = sorted_edges[beg + k];
        const uint2 d = *(const uint2*)&support2[(ev.x << 4) + 4 * c];
        const half2v* hp = (const half2v*)&d;
        const _Float16 wh = (_Float16)__int_as_float(ev.y);
        const half2v w2 = {wh, wh};
        a01 += w2 * hp[0];
        a23 += w2 * hp[1];
    }

    float acc0 = (float)a01[0], acc1 = (float)a01[1];
    float acc2 = (float)a23[0], acc3 = (float)a23[1];
    acc0 += __shfl_xor(acc0, 4, 16); acc0 += __shfl_xor(acc0, 8, 16);
    acc1 += __shfl_xor(acc1, 4, 16); acc1 += __shfl_xor(acc1, 8, 16);
    acc2 += __shfl_xor(acc2, 4, 16); acc2 += __shfl_xor(acc2, 8, 16);
    acc3 += __shfl_xor(acc3, 4, 16); acc3 += __shfl_xor(acc3, 8, 16);

    const float v0 = acc0 + b2s[4 * c];
    const float v1 = acc1 + b2s[4 * c + 1];
    const float v2 = acc2 + b2s[4 * c + 2];
    const float v3 = acc3 + b2s[4 * c + 3];
    float m = fmaxf(fmaxf(v0, v1), fmaxf(v2, v3));
    m = fmaxf(m, __shfl_xor(m, 1, 16));
    m = fmaxf(m, __shfl_xor(m, 2, 16));
    float sum = __expf(v0 - m) + __expf(v1 - m) + __expf(v2 - m) + __expf(v3 - m);
    sum += __shfl_xor(sum, 1, 16);
    sum += __shfl_xor(sum, 2, 16);
    if (p == 0) {
        const float lse = m + __logf(sum);
        float4 o = make_float4(v0 - lse, v1 - lse, v2 - lse, v3 - lse);
        *(float4*)&out[(size_t)node * F_OUT + 4 * c] = o;
    }
}

// ---------------------------------------------------------------------------
extern "C" void kernel_launch(void* const* d_in, const int* in_sizes, int n_in,
                              void* d_out, int out_size, void* d_ws, size_t ws_size,
                              hipStream_t stream) {
    const float* x     = (const float*)d_in[0];
    const int*   esrc  = (const int*)  d_in[1];
    const int*   edst  = (const int*)  d_in[2];
    const float* evals = (const float*)d_in[3];
    const float* W1    = (const float*)d_in[4];
    const float* b1    = (const float*)d_in[5];
    const float* W2    = (const float*)d_in[6];
    const float* b2    = (const float*)d_in[7];
    float* out = (float*)d_out;

    // Workspace layout (~45.7 MB); all segments 16 B-aligned.
    char* ws = (char*)d_ws;
    _Float16* support1     = (_Float16*)(ws);              // 12,800,000 B
    _Float16* support2     = (_Float16*)(ws + 12800000);   //  3,200,000 B
    int2*     tmp          = (int2*)    (ws + 16000000);   // 14,413,824 B (NBKT*CAP*8)
    int2*     sorted_edges = (int2*)    (ws + 30413824);   // 14,413,824 B
    int*      rowstart     = (int*)     (ws + 44827648);   //    400,000 B
    int*      deg          = (int*)     (ws + 45227648);   //    400,000 B
    int*      bucketCursor = (int*)     (ws + 45627648);   //      1,568 B
    _Float16* W1h          = (_Float16*)(ws + 45629216);   //     32,768 B

    prep_kernel<<<64, 256, 0, stream>>>(W1, W1h, bucketCursor);
    gemm1_passA_kernel<<<GEMM1_BLOCKS + PA_BLOCKS, 256, 0, stream>>>(
        x, W1h, support1, esrc, edst, evals, bucketCursor, tmp);
    passB_kernel<<<NBKT, 256, 0, stream>>>(tmp, bucketCursor, sorted_edges, rowstart, deg);
    spmm1_fused_kernel<<<N_NODES / 4, 256, 0, stream>>>(rowstart, deg, sorted_edges,
                                                        support1, b1, W2, support2);
    spmm2_fused_kernel<<<N_NODES / 16, 256, 0, stream>>>(rowstart, deg, sorted_edges,
                                                         support2, b2, out);
}